// Round 1
// 254.129 us; speedup vs baseline: 1.4923x; 1.4923x over previous
//
#include <hip/hip_runtime.h>
#include <math.h>

#define KNN 64

typedef unsigned long long u64;

// Value pipeline (bitwise-verified vs harness np ref, r17 absmax=0) — UNCHANGED:
//   sq  = (x0^2+x2^2) + (x1^2+x3^2)   (noFMA halving butterfly)
//   dot = asc-k FMA chain
//   d2  = (sq_i + sq_j) - 2*dot       (C1)
// Tie rule: bit-equal d2 ordered by ASCENDING index; equal-to-rank-63 -> no-op.
// This version unifies the sort key as u64 (d2bits<<32 | local_idx): keys are
// globally unique and earlier chunks have smaller idx, so plain u64 ascending
// order IS the required tie order — both the serial-insert path and the
// bitonic sort/merge path inherit tie correctness structurally.

__device__ __forceinline__ unsigned dpp_shr1_z(unsigned v) {
    // dpp_ctrl 0x138 = wave_shr:1; bound_ctrl=1 -> lane0 receives 0 (acts as -inf key)
    return (unsigned)__builtin_amdgcn_update_dpp(0, (int)v, 0x138, 0xF, 0xF, true);
}

// Cross-lane exchange of a u64 with partner lane^J.
// J<=16: ds_swizzle xor-mode (imm, no address math). J==32: ds_bpermute with
// precomputed byte address.
template<int J>
__device__ __forceinline__ u64 kv_exch(u64 kv, int addr32) {
    unsigned lo = (unsigned)kv, hi = (unsigned)(kv >> 32);
    unsigned rlo, rhi;
    if constexpr (J <= 16) {
        rlo = (unsigned)__builtin_amdgcn_ds_swizzle((int)lo, (J << 10) | 0x1F);
        rhi = (unsigned)__builtin_amdgcn_ds_swizzle((int)hi, (J << 10) | 0x1F);
    } else {
        rlo = (unsigned)__builtin_amdgcn_ds_bpermute(addr32, (int)lo);
        rhi = (unsigned)__builtin_amdgcn_ds_bpermute(addr32, (int)hi);
    }
    return ((u64)rhi << 32) | (u64)rlo;
}

// One bitonic compare-exchange stage: partner = lane^J, block size K.
// take_min = ((lane&K)==0) == ((lane&J)==0)  (ascending final order).
template<int K, int J>
__device__ __forceinline__ void ce(u64 &kv, int lane, int addr32) {
    const u64 r = kv_exch<J>(kv, addr32);
    const bool tm = ((lane & K) == 0) == ((lane & J) == 0);
    kv = ((kv < r) == tm) ? kv : r;
}

// Final bitonic clean (merge of a bitonic sequence into ascending order).
__device__ __forceinline__ void clean64(u64 &kv, int lane, int addr32) {
    ce<64,32>(kv, lane, addr32);
    ce<64,16>(kv, lane, addr32);
    ce<64, 8>(kv, lane, addr32);
    ce<64, 4>(kv, lane, addr32);
    ce<64, 2>(kv, lane, addr32);
    ce<64, 1>(kv, lane, addr32);
}

// Full ascending bitonic sort of 64 u64 keys (one per lane), 21 stages.
__device__ __forceinline__ u64 sort64(u64 kv, int lane, int addr32) {
    ce<2,1>(kv, lane, addr32);
    ce<4,2>(kv, lane, addr32);   ce<4,1>(kv, lane, addr32);
    ce<8,4>(kv, lane, addr32);   ce<8,2>(kv, lane, addr32);   ce<8,1>(kv, lane, addr32);
    ce<16,8>(kv, lane, addr32);  ce<16,4>(kv, lane, addr32);  ce<16,2>(kv, lane, addr32);  ce<16,1>(kv, lane, addr32);
    ce<32,16>(kv, lane, addr32); ce<32,8>(kv, lane, addr32);  ce<32,4>(kv, lane, addr32);  ce<32,2>(kv, lane, addr32);  ce<32,1>(kv, lane, addr32);
    clean64(kv, lane, addr32);
    return kv;
}

__global__ __launch_bounds__(256) void knn_wave_kernel(
    const float4* __restrict__ coords,
    float* __restrict__ outIdx,
    float* __restrict__ outDist,
    int S, int Nq)
{
#pragma clang fp contract(off)
    const int lane = threadIdx.x & 63;
    const int q    = (blockIdx.x << 2) + (threadIdx.x >> 6);   // 4 waves/block
    if (q >= Nq) return;                                       // wave-uniform
    const int seg_start = (q / S) * S;
    const float4* __restrict__ seg = coords + seg_start;

    const float4 x = coords[q];
    const float sqx = (x.x * x.x + x.z * x.z) + (x.y * x.y + x.w * x.w);

    const int addr32 = (lane ^ 32) << 2;   // bpermute byte addr for partner lane^32
    const int addr63 = (lane ^ 63) << 2;   // bpermute byte addr for wave reversal

    // ---- chunk 0: compute 64 keys, full bitonic sort -> initialized list ----
    u64 kv;
    {
        const float4 c = seg[lane];
        const float csq = (c.x * c.x + c.z * c.z) + (c.y * c.y + c.w * c.w);
        const float dot = __builtin_fmaf(x.w, c.w,
                          __builtin_fmaf(x.z, c.z,
                          __builtin_fmaf(x.y, c.y, x.x * c.x)));
        const float t1  = sqx + csq;
        const float d2  = t1 - 2.0f * dot;
        unsigned b = __float_as_uint(d2);
        b ^= (unsigned)((int)b >> 31) | 0x80000000u;            // order-preserving
        kv = ((u64)b << 32) | (unsigned)lane;
    }
    kv = sort64(kv, lane, addr32);
    unsigned worst = (unsigned)__builtin_amdgcn_readlane((int)(unsigned)(kv >> 32), 63);

    for (int c0 = 64; c0 < S; c0 += 64) {
        const int j = c0 + lane;
        const float4 c = seg[j];
        const float csq = (c.x * c.x + c.z * c.z) + (c.y * c.y + c.w * c.w);
        const float dot = __builtin_fmaf(x.w, c.w,
                          __builtin_fmaf(x.z, c.z,
                          __builtin_fmaf(x.y, c.y, x.x * c.x)));
        const float t1  = sqx + csq;
        const float d2  = t1 - 2.0f * dot;
        unsigned b = __float_as_uint(d2);
        b ^= (unsigned)((int)b >> 31) | 0x80000000u;

        // survivors vs pre-chunk threshold; b==worst correctly excluded
        // (its u64 key exceeds the rank-63 key since its idx is larger)
        unsigned long long mask = __ballot(b < worst);
        const int cnt = __popcll(mask);

        if (cnt >= 20) {
            // ---- dense chunk: bitonic sort the whole chunk, merge with list ----
            u64 ckv = ((u64)b << 32) | (unsigned)j;
            ckv = sort64(ckv, lane, addr32);
            // L[i] = min(list[i], chunk[63-i]) -> bitonic seq holding lowest 64
            {
                const unsigned rlo = (unsigned)__builtin_amdgcn_ds_bpermute(addr63, (int)(unsigned)ckv);
                const unsigned rhi = (unsigned)__builtin_amdgcn_ds_bpermute(addr63, (int)(unsigned)(ckv >> 32));
                const u64 r = ((u64)rhi << 32) | (u64)rlo;
                kv = (r < kv) ? r : kv;
            }
            clean64(kv, lane, addr32);
        } else {
            // ---- sparse chunk: slim serial insert (no per-insert ballot/popc) ----
            while (mask) {
                const int s = (int)__builtin_ctzll(mask);       // SALU, asc idx
                mask &= mask - 1;
                const unsigned cd = (unsigned)__builtin_amdgcn_readlane((int)b, s);
                const u64 ckv = ((u64)cd << 32) | (unsigned)(c0 + s);   // SGPR pair
                const unsigned udlo = dpp_shr1_z((unsigned)kv);
                const unsigned udhi = dpp_shr1_z((unsigned)(kv >> 32));
                const u64 ud = ((u64)udhi << 32) | (u64)udlo;   // list[l-1], lane0 -> 0
                // sorted-insert identity: list[l-1] <= list[l] always, so
                //   keep      (kv < ckv)            : lanes before insert pos
                //   insert    (!keep && ud < ckv)   : exactly the insert lane
                //   shift     (otherwise)           : lanes after insert pos
                // ckv > all keys -> keep everywhere -> no-op (rank-63 rule)
                const bool keep = kv < ckv;
                const bool ins  = ud < ckv;
                kv = keep ? kv : (ins ? ckv : ud);
            }
        }
        worst = (unsigned)__builtin_amdgcn_readlane((int)(unsigned)(kv >> 32), 63);
    }

    // lane l holds rank l: fully coalesced 64-wide stores
    const unsigned idxs = (unsigned)kv;
    unsigned bk = (unsigned)(kv >> 32);
    bk ^= ((bk & 0x80000000u) ? 0x80000000u : 0xFFFFFFFFu);     // undo transform
    const float d2 = __uint_as_float(bk);
    outIdx [(size_t)q * KNN + lane] = (float)(seg_start + (int)idxs);
    outDist[(size_t)q * KNN + lane] = fmaxf(d2, 0.0f);
}

extern "C" void kernel_launch(void* const* d_in, const int* in_sizes, int n_in,
                              void* d_out, int out_size, void* d_ws, size_t ws_size,
                              hipStream_t stream) {
    const float* coords = (const float*)d_in[1];
    const int N = in_sizes[1] / 4;
    const int B = in_sizes[2] - 1;
    const int S = N / B;
    (void)n_in; (void)d_ws; (void)ws_size; (void)out_size;

    float* outIdx  = (float*)d_out;
    float* outDist = outIdx + (size_t)N * KNN;

    const int blocks = (N + 3) / 4;   // 4 waves (queries) per 256-thread block
    knn_wave_kernel<<<blocks, 256, 0, stream>>>((const float4*)coords,
                                                outIdx, outDist, S, N);
}

// Round 2
// 191.521 us; speedup vs baseline: 1.9801x; 1.3269x over previous
//
#include <hip/hip_runtime.h>
#include <math.h>

#define KNN 64

typedef unsigned long long u64;

// Value pipeline (bitwise-verified vs harness np ref, r17 absmax=0) — UNCHANGED MATH:
//   sq  = (x0^2+x2^2) + (x1^2+x3^2)   (noFMA halving butterfly; fp contract OFF)
//   dot = asc-k FMA chain
//   d2  = (sq_i + sq_j) - 2*dot       == fmaf(-2, dot, sq_i+sq_j)  (2*dot exact,
//         single rounding either way -> bit-identical to r1's t1 - 2.0f*dot)
// Keys are u64 (d2bits<<32 | local_idx): unique, ascending u64 order == required
// tie order (equal d2 -> ascending index; equal-to-rank-63 -> no-op, since the
// candidate's idx always exceeds every listed idx at ballot time).
//
// r2 structure: csq precomputed in LDS (shared by the 4 waves of a block, which
// all scan the same segment); survivors buffered into a per-wave 64-slot LDS
// buffer (pos = bufcnt + mbcnt, no per-survivor SALU loop); buffer flushed via
// sort64 + reversal-merge + clean64 when it would overflow. Ballot threshold is
// stale between flushes but always >= the exact running 64th key, so flushes
// reconstruct the exact top-64 (superset argument).

// Cross-lane exchange of a u64 with partner lane^J.
template<int J>
__device__ __forceinline__ u64 kv_exch(u64 kv, int addr32) {
    unsigned lo = (unsigned)kv, hi = (unsigned)(kv >> 32);
    unsigned rlo, rhi;
    if constexpr (J <= 16) {
        rlo = (unsigned)__builtin_amdgcn_ds_swizzle((int)lo, (J << 10) | 0x1F);
        rhi = (unsigned)__builtin_amdgcn_ds_swizzle((int)hi, (J << 10) | 0x1F);
    } else {
        rlo = (unsigned)__builtin_amdgcn_ds_bpermute(addr32, (int)lo);
        rhi = (unsigned)__builtin_amdgcn_ds_bpermute(addr32, (int)hi);
    }
    return ((u64)rhi << 32) | (u64)rlo;
}

// One bitonic compare-exchange stage: partner = lane^J, block size K.
template<int K, int J>
__device__ __forceinline__ void ce(u64 &kv, int lane, int addr32) {
    const u64 r = kv_exch<J>(kv, addr32);
    const bool tm = ((lane & K) == 0) == ((lane & J) == 0);
    kv = ((kv < r) == tm) ? kv : r;
}

__device__ __forceinline__ void clean64(u64 &kv, int lane, int addr32) {
    ce<64,32>(kv, lane, addr32);
    ce<64,16>(kv, lane, addr32);
    ce<64, 8>(kv, lane, addr32);
    ce<64, 4>(kv, lane, addr32);
    ce<64, 2>(kv, lane, addr32);
    ce<64, 1>(kv, lane, addr32);
}

__device__ __forceinline__ u64 sort64(u64 kv, int lane, int addr32) {
    ce<2,1>(kv, lane, addr32);
    ce<4,2>(kv, lane, addr32);   ce<4,1>(kv, lane, addr32);
    ce<8,4>(kv, lane, addr32);   ce<8,2>(kv, lane, addr32);   ce<8,1>(kv, lane, addr32);
    ce<16,8>(kv, lane, addr32);  ce<16,4>(kv, lane, addr32);  ce<16,2>(kv, lane, addr32);  ce<16,1>(kv, lane, addr32);
    ce<32,16>(kv, lane, addr32); ce<32,8>(kv, lane, addr32);  ce<32,4>(kv, lane, addr32);  ce<32,2>(kv, lane, addr32);  ce<32,1>(kv, lane, addr32);
    clean64(kv, lane, addr32);
    return kv;
}

// Flush: merge the (∞-padded) 64-slot buffer into the sorted list, tighten
// worst, and reset the buffer to ∞.
__device__ __forceinline__ void flush_merge(u64 &kv, unsigned &worst,
                                            u64* __restrict__ s_buf,
                                            int lane, int addr32, int addr63) {
    u64 kvb = s_buf[lane];
    kvb = sort64(kvb, lane, addr32);
    // reversal-merge: kv[i] = min(list[i], buf_sorted[63-i]) -> bitonic
    const unsigned rlo = (unsigned)__builtin_amdgcn_ds_bpermute(addr63, (int)(unsigned)kvb);
    const unsigned rhi = (unsigned)__builtin_amdgcn_ds_bpermute(addr63, (int)(unsigned)(kvb >> 32));
    const u64 r = ((u64)rhi << 32) | (u64)rlo;
    kv = (r < kv) ? r : kv;
    clean64(kv, lane, addr32);
    worst = (unsigned)__builtin_amdgcn_readlane((int)(unsigned)(kv >> 32), 63);
    s_buf[lane] = ~0ull;   // ∞-pad for next fill (same-wave, LDS ops in order)
}

__global__ __launch_bounds__(256) void knn_wave_kernel(
    const float4* __restrict__ coords,
    float* __restrict__ outIdx,
    float* __restrict__ outDist,
    int S, int Nq)
{
#pragma clang fp contract(off)
    extern __shared__ u64 smem_u64[];              // [S/2] csq floats + 4*64 u64 buf
    float* __restrict__ s_csq = (float*)smem_u64;

    const int tid   = threadIdx.x;
    const int lane  = tid & 63;
    const int wid   = tid >> 6;
    const int qbase = blockIdx.x << 2;             // 4 queries/block, same segment
    const int seg_start = (qbase / S) * S;         // S % 4 == 0 assumed (S=4096)

    // ---- cooperative csq fill (identical butterfly, contract off) ----
    for (int p = tid; p < S; p += 256) {
        const float4 c = coords[seg_start + p];
        s_csq[p] = (c.x * c.x + c.z * c.z) + (c.y * c.y + c.w * c.w);
    }
    __syncthreads();

    const int q = qbase + wid;
    if (q >= Nq) return;                           // wave-uniform, after sync

    u64* __restrict__ s_buf = smem_u64 + (S >> 1) + (wid << 6);  // 64 slots/wave
    const float4* __restrict__ seg = coords + seg_start;

    const float4 x = coords[q];
    const float sqx = (x.x * x.x + x.z * x.z) + (x.y * x.y + x.w * x.w);

    const int addr32 = (lane ^ 32) << 2;
    const int addr63 = (lane ^ 63) << 2;

    // ---- chunk 0: full bitonic sort -> initial list ----
    u64 kv;
    {
        const float4 c = seg[lane];
        const float csq = s_csq[lane];
        const float dot = __builtin_fmaf(x.w, c.w,
                          __builtin_fmaf(x.z, c.z,
                          __builtin_fmaf(x.y, c.y, x.x * c.x)));
        const float t1  = sqx + csq;
        const float d2  = __builtin_fmaf(-2.0f, dot, t1);
        unsigned b = __float_as_uint(d2);
        b ^= (unsigned)((int)b >> 31) | 0x80000000u;
        kv = ((u64)b << 32) | (unsigned)lane;
    }
    kv = sort64(kv, lane, addr32);
    unsigned worst = (unsigned)__builtin_amdgcn_readlane((int)(unsigned)(kv >> 32), 63);

    s_buf[lane] = ~0ull;                           // ∞-pad buffer
    int bufcnt = 0;

    for (int c0 = 64; c0 < S; c0 += 64) {
        const int j = c0 + lane;
        const float4 c = seg[j];
        const float csq = s_csq[j];
        const float dot = __builtin_fmaf(x.w, c.w,
                          __builtin_fmaf(x.z, c.z,
                          __builtin_fmaf(x.y, c.y, x.x * c.x)));
        const float t1  = sqx + csq;
        const float d2  = __builtin_fmaf(-2.0f, dot, t1);
        unsigned b = __float_as_uint(d2);
        b ^= (unsigned)((int)b >> 31) | 0x80000000u;

        bool surv = b < worst;                     // strict: == worst-hi excluded
        u64 mask = __ballot(surv);
        int cnt = __popcll(mask);

        if (bufcnt + cnt > 64) {                   // wave-uniform
            flush_merge(kv, worst, s_buf, lane, addr32, addr63);
            bufcnt = 0;
            surv = b < worst;                      // re-ballot vs tightened worst
            mask = __ballot(surv);
            cnt = __popcll(mask);
        }

        const int pos = __builtin_amdgcn_mbcnt_hi(
                            (unsigned)(mask >> 32),
                            __builtin_amdgcn_mbcnt_lo((unsigned)mask, bufcnt));
        if (surv)
            s_buf[pos] = ((u64)b << 32) | (unsigned)j;
        bufcnt += cnt;
    }

    if (bufcnt > 0)
        flush_merge(kv, worst, s_buf, lane, addr32, addr63);

    // lane l holds rank l: fully coalesced 64-wide stores
    const unsigned idxs = (unsigned)kv;
    unsigned bk = (unsigned)(kv >> 32);
    bk ^= ((bk & 0x80000000u) ? 0x80000000u : 0xFFFFFFFFu);
    const float d2 = __uint_as_float(bk);
    outIdx [(size_t)q * KNN + lane] = (float)(seg_start + (int)idxs);
    outDist[(size_t)q * KNN + lane] = fmaxf(d2, 0.0f);
}

extern "C" void kernel_launch(void* const* d_in, const int* in_sizes, int n_in,
                              void* d_out, int out_size, void* d_ws, size_t ws_size,
                              hipStream_t stream) {
    const float* coords = (const float*)d_in[1];
    const int N = in_sizes[1] / 4;
    const int B = in_sizes[2] - 1;
    const int S = N / B;
    (void)n_in; (void)d_ws; (void)ws_size; (void)out_size;

    float* outIdx  = (float*)d_out;
    float* outDist = outIdx + (size_t)N * KNN;

    const int blocks = (N + 3) / 4;                // 4 waves (queries) per block
    const size_t smem = (size_t)S * 4 + 4 * 64 * 8;  // csq + 4 wave buffers
    knn_wave_kernel<<<blocks, 256, smem, stream>>>((const float4*)coords,
                                                   outIdx, outDist, S, N);
}

// Round 3
// 187.806 us; speedup vs baseline: 2.0193x; 1.0198x over previous
//
#include <hip/hip_runtime.h>
#include <math.h>

#define KNN 64

typedef unsigned long long u64;

// Value pipeline (bitwise-verified vs harness np ref; r2 absmax=0) — UNCHANGED MATH:
//   csq = (x0^2+x2^2) + (x1^2+x3^2)   (noFMA halving butterfly; fp contract OFF)
//   dot = asc-k FMA chain
//   d2  = fmaf(-2, dot, sqx+csq)      (bit-identical to (sqx+csq) - 2*dot)
// Sort keys are u64 (transformed_d2_bits<<32 | local_idx): unique; ascending u64
// order == required tie order (equal d2 -> ascending index; candidate equal to
// rank-63 -> no-op since its idx exceeds every listed idx at ballot time).
//
// r3 changes (selection semantics unchanged):
//  - ballot in FLOAT domain (d2 < worst_f); valid because d2 is never NaN and
//    never -0.0 (exact cancellation rounds to +0), so float order == bit order.
//  - buffer slots hold RAW d2 bits + idx; sign-fix transform deferred to flush
//    (once per flush instead of once per chunk). Pad = {+inf bits, ~0} which
//    transforms to the u64 maximum.
//  - x4 chunk unroll: one address update per 4 chunks (imm-offset loads), ILP
//    across the 4 independent d2 chains.
//  - chunk 0 routes through the same buffer path (list starts all-pad,
//    worst_f = +inf): first flush reconstructs sorted chunk 0 exactly.

// Cross-lane exchange of a u64 with partner lane^J.
template<int J>
__device__ __forceinline__ u64 kv_exch(u64 kv, int addr32) {
    unsigned lo = (unsigned)kv, hi = (unsigned)(kv >> 32);
    unsigned rlo, rhi;
    if constexpr (J <= 16) {
        rlo = (unsigned)__builtin_amdgcn_ds_swizzle((int)lo, (J << 10) | 0x1F);
        rhi = (unsigned)__builtin_amdgcn_ds_swizzle((int)hi, (J << 10) | 0x1F);
    } else {
        rlo = (unsigned)__builtin_amdgcn_ds_bpermute(addr32, (int)lo);
        rhi = (unsigned)__builtin_amdgcn_ds_bpermute(addr32, (int)hi);
    }
    return ((u64)rhi << 32) | (u64)rlo;
}

// One bitonic compare-exchange stage: partner = lane^J, block size K.
template<int K, int J>
__device__ __forceinline__ void ce(u64 &kv, int lane, int addr32) {
    const u64 r = kv_exch<J>(kv, addr32);
    const bool tm = ((lane & K) == 0) == ((lane & J) == 0);
    kv = ((kv < r) == tm) ? kv : r;
}

__device__ __forceinline__ void clean64(u64 &kv, int lane, int addr32) {
    ce<64,32>(kv, lane, addr32);
    ce<64,16>(kv, lane, addr32);
    ce<64, 8>(kv, lane, addr32);
    ce<64, 4>(kv, lane, addr32);
    ce<64, 2>(kv, lane, addr32);
    ce<64, 1>(kv, lane, addr32);
}

__device__ __forceinline__ u64 sort64(u64 kv, int lane, int addr32) {
    ce<2,1>(kv, lane, addr32);
    ce<4,2>(kv, lane, addr32);   ce<4,1>(kv, lane, addr32);
    ce<8,4>(kv, lane, addr32);   ce<8,2>(kv, lane, addr32);   ce<8,1>(kv, lane, addr32);
    ce<16,8>(kv, lane, addr32);  ce<16,4>(kv, lane, addr32);  ce<16,2>(kv, lane, addr32);  ce<16,1>(kv, lane, addr32);
    ce<32,16>(kv, lane, addr32); ce<32,8>(kv, lane, addr32);  ce<32,4>(kv, lane, addr32);  ce<32,2>(kv, lane, addr32);  ce<32,1>(kv, lane, addr32);
    clean64(kv, lane, addr32);
    return kv;
}

#define PAD_RAW 0x7F800000FFFFFFFFull   // raw:+inf bits, idx:~0 -> transforms to u64 max

// Flush: transform raw buffer -> sort keys, bitonic sort, reversal-merge into
// the sorted list, clean, tighten worst_f, reset buffer to pad.
__device__ __forceinline__ void flush_merge(u64 &kv, float &worst_f,
                                            u64* __restrict__ s_buf,
                                            int lane, int addr32, int addr63) {
    const u64 raw = s_buf[lane];
    unsigned hi = (unsigned)(raw >> 32);
    hi ^= (unsigned)((int)hi >> 31) | 0x80000000u;           // order-preserving
    u64 kvb = ((u64)hi << 32) | (unsigned)raw;
    kvb = sort64(kvb, lane, addr32);
    // reversal-merge: kv[i] = min(list[i], buf_sorted[63-i]) -> bitonic
    const unsigned rlo = (unsigned)__builtin_amdgcn_ds_bpermute(addr63, (int)(unsigned)kvb);
    const unsigned rhi = (unsigned)__builtin_amdgcn_ds_bpermute(addr63, (int)(unsigned)(kvb >> 32));
    const u64 r = ((u64)rhi << 32) | (u64)rlo;
    kv = (r < kv) ? r : kv;
    clean64(kv, lane, addr32);
    unsigned w = (unsigned)__builtin_amdgcn_readlane((int)(unsigned)(kv >> 32), 63);
    w ^= (w & 0x80000000u) ? 0x80000000u : 0xFFFFFFFFu;      // untransform (pad -> +inf)
    worst_f = __uint_as_float(w);
    s_buf[lane] = PAD_RAW;
}

__global__ __launch_bounds__(256) void knn_wave_kernel(
    const float4* __restrict__ coords,
    float* __restrict__ outIdx,
    float* __restrict__ outDist,
    int S, int Nq)
{
#pragma clang fp contract(off)
    extern __shared__ u64 smem_u64[];              // [S/2] csq floats + 4*64 u64 buf
    float* __restrict__ s_csq = (float*)smem_u64;

    const int tid   = threadIdx.x;
    const int lane  = tid & 63;
    const int wid   = tid >> 6;
    const int qbase = blockIdx.x << 2;             // 4 queries/block, same segment
    const int seg_start = (qbase / S) * S;         // S % 4 == 0 (S=4096)

    // ---- cooperative csq fill (identical butterfly, contract off) ----
    for (int p = tid; p < S; p += 256) {
        const float4 c = coords[seg_start + p];
        s_csq[p] = (c.x * c.x + c.z * c.z) + (c.y * c.y + c.w * c.w);
    }
    __syncthreads();

    const int q = qbase + wid;
    if (q >= Nq) return;                           // wave-uniform, after sync

    u64* __restrict__ s_buf = smem_u64 + (S >> 1) + (wid << 6);  // 64 slots/wave
    const float4* __restrict__ seg = coords + seg_start;

    const float4 x = coords[q];
    const float sqx = (x.x * x.x + x.z * x.z) + (x.y * x.y + x.w * x.w);

    const int addr32 = (lane ^ 32) << 2;
    const int addr63 = (lane ^ 63) << 2;

    u64 kv = 0xFF800000FFFFFFFFull;                // all-pad sorted list (transformed)
    float worst_f = __builtin_inff();
    s_buf[lane] = PAD_RAW;
    int bufcnt = 0;

    const int S4 = S & ~255;                       // main: 4 chunks per iteration
    for (int c0 = 0; c0 < S4; c0 += 256) {
#pragma unroll
        for (int u = 0; u < 4; ++u) {
            const int base = c0 + (u << 6);
            const int j = base + lane;
            const float4 c = seg[j];               // imm-offset foldable (±4KB)
            const float csq = s_csq[j];
            const float dot = __builtin_fmaf(x.w, c.w,
                              __builtin_fmaf(x.z, c.z,
                              __builtin_fmaf(x.y, c.y, x.x * c.x)));
            const float d2  = __builtin_fmaf(-2.0f, dot, sqx + csq);

            bool surv = d2 < worst_f;              // float order == key order here
            u64 m = __ballot(surv);
            int cnt = __popcll(m);
            if (bufcnt + cnt > 64) {               // wave-uniform
                flush_merge(kv, worst_f, s_buf, lane, addr32, addr63);
                bufcnt = 0;
                surv = d2 < worst_f;               // re-ballot vs tightened worst
                m = __ballot(surv);
                cnt = __popcll(m);
            }
            const int pos = __builtin_amdgcn_mbcnt_hi(
                                (unsigned)(m >> 32),
                                __builtin_amdgcn_mbcnt_lo((unsigned)m, bufcnt));
            if (surv)
                s_buf[pos] = ((u64)__float_as_uint(d2) << 32) | (unsigned)j;
            bufcnt += cnt;
        }
    }
    for (int c0 = S4; c0 < S; c0 += 64) {          // generic tail (S%256!=0 safety)
        const int j = c0 + lane;
        const float4 c = seg[j];
        const float csq = s_csq[j];
        const float dot = __builtin_fmaf(x.w, c.w,
                          __builtin_fmaf(x.z, c.z,
                          __builtin_fmaf(x.y, c.y, x.x * c.x)));
        const float d2  = __builtin_fmaf(-2.0f, dot, sqx + csq);
        bool surv = d2 < worst_f;
        u64 m = __ballot(surv);
        int cnt = __popcll(m);
        if (bufcnt + cnt > 64) {
            flush_merge(kv, worst_f, s_buf, lane, addr32, addr63);
            bufcnt = 0;
            surv = d2 < worst_f;
            m = __ballot(surv);
            cnt = __popcll(m);
        }
        const int pos = __builtin_amdgcn_mbcnt_hi(
                            (unsigned)(m >> 32),
                            __builtin_amdgcn_mbcnt_lo((unsigned)m, bufcnt));
        if (surv)
            s_buf[pos] = ((u64)__float_as_uint(d2) << 32) | (unsigned)j;
        bufcnt += cnt;
    }

    if (bufcnt > 0)
        flush_merge(kv, worst_f, s_buf, lane, addr32, addr63);

    // lane l holds rank l: fully coalesced 64-wide stores
    const unsigned idxs = (unsigned)kv;
    unsigned bk = (unsigned)(kv >> 32);
    bk ^= ((bk & 0x80000000u) ? 0x80000000u : 0xFFFFFFFFu);  // undo transform
    const float d2 = __uint_as_float(bk);
    outIdx [(size_t)q * KNN + lane] = (float)(seg_start + (int)idxs);
    outDist[(size_t)q * KNN + lane] = fmaxf(d2, 0.0f);
}

extern "C" void kernel_launch(void* const* d_in, const int* in_sizes, int n_in,
                              void* d_out, int out_size, void* d_ws, size_t ws_size,
                              hipStream_t stream) {
    const float* coords = (const float*)d_in[1];
    const int N = in_sizes[1] / 4;
    const int B = in_sizes[2] - 1;
    const int S = N / B;
    (void)n_in; (void)d_ws; (void)ws_size; (void)out_size;

    float* outIdx  = (float*)d_out;
    float* outDist = outIdx + (size_t)N * KNN;

    const int blocks = (N + 3) / 4;                // 4 waves (queries) per block
    const size_t smem = (size_t)S * 4 + 4 * 64 * 8;  // csq + 4 wave buffers
    knn_wave_kernel<<<blocks, 256, smem, stream>>>((const float4*)coords,
                                                   outIdx, outDist, S, N);
}

// Round 6
// 184.226 us; speedup vs baseline: 2.0586x; 1.0194x over previous
//
#include <hip/hip_runtime.h>
#include <math.h>

#define KNN 64

typedef unsigned long long u64;

// Value pipeline (bitwise-verified vs harness np ref; r2/r3 absmax=0) — UNCHANGED:
//   csq = (x0^2+x2^2) + (x1^2+x3^2)   (noFMA butterfly; fp contract OFF)
//   dot = asc-k FMA chain
//   d2  = fmaf(-2, dot, sqx+csq)
// Keys: u64 (transformed_d2_bits<<32 | local_idx) — unique; ascending u64 order
// == required tie order. Ballot in float domain (no NaN, no -0.0 possible).
//
// r5 (resubmitted r6 — previous bench died on container infra, kernel never ran):
// r4's VALU-exchange experiment FAILED correctness (absmax 1.1e9) — one of
// {row_ror:4/12 xor4, v_permlane16_swap, v_permlane32_swap} has semantics
// different from the model. This version keeps ONLY the direction-proof DPP
// conversions (self-inverse permutations, correct under either convention):
//   J=1 : quad_perm [1,0,3,2] (0xB1)     J=2 : quad_perm [2,3,0,1] (0x4E)
//   J=8 : row_ror:8 (l -> (l±8) mod 16 == l^8 either direction)
// and reverts J=4, J=16 to r3-verified ds_swizzle, J=32 to r3-verified
// ds_bpermute. 17 of 27 flush exchange stages leave the DS serial chain.

template<int CTRL>
__device__ __forceinline__ unsigned dpp32(unsigned v) {
    // same (old, src, ctrl, 0xF, 0xF, false) pattern as the r0-verified wave_shr
    return (unsigned)__builtin_amdgcn_update_dpp((int)v, (int)v, CTRL, 0xF, 0xF, false);
}

// Cross-lane exchange of a u64 with partner lane^J.
// J in {1,2,8}: VALU DPP (direction-proof patterns only).
// J in {4,16}: ds_swizzle xor-mode (r3-verified). J=32: ds_bpermute (r3-verified).
template<int J>
__device__ __forceinline__ u64 kv_exch(u64 kv, int addr32) {
    unsigned lo = (unsigned)kv, hi = (unsigned)(kv >> 32);
    unsigned rlo, rhi;
    if constexpr (J == 1) {            // quad_perm [1,0,3,2], self-inverse
        rlo = dpp32<0xB1>(lo); rhi = dpp32<0xB1>(hi);
    } else if constexpr (J == 2) {     // quad_perm [2,3,0,1], self-inverse
        rlo = dpp32<0x4E>(lo); rhi = dpp32<0x4E>(hi);
    } else if constexpr (J == 8) {     // row_ror:8 == xor8 (symmetric)
        rlo = dpp32<0x128>(lo); rhi = dpp32<0x128>(hi);
    } else if constexpr (J == 4 || J == 16) {
        rlo = (unsigned)__builtin_amdgcn_ds_swizzle((int)lo, (J << 10) | 0x1F);
        rhi = (unsigned)__builtin_amdgcn_ds_swizzle((int)hi, (J << 10) | 0x1F);
    } else {                           // J == 32
        rlo = (unsigned)__builtin_amdgcn_ds_bpermute(addr32, (int)lo);
        rhi = (unsigned)__builtin_amdgcn_ds_bpermute(addr32, (int)hi);
    }
    return ((u64)rhi << 32) | (u64)rlo;
}

// One bitonic compare-exchange stage: partner = lane^J, block size K.
template<int K, int J>
__device__ __forceinline__ void ce(u64 &kv, int lane, int addr32) {
    const u64 r = kv_exch<J>(kv, addr32);
    const bool tm = ((lane & K) == 0) == ((lane & J) == 0);
    kv = ((kv < r) == tm) ? kv : r;
}

__device__ __forceinline__ void clean64(u64 &kv, int lane, int addr32) {
    ce<64,32>(kv, lane, addr32);
    ce<64,16>(kv, lane, addr32);
    ce<64, 8>(kv, lane, addr32);
    ce<64, 4>(kv, lane, addr32);
    ce<64, 2>(kv, lane, addr32);
    ce<64, 1>(kv, lane, addr32);
}

__device__ __forceinline__ u64 sort64(u64 kv, int lane, int addr32) {
    ce<2,1>(kv, lane, addr32);
    ce<4,2>(kv, lane, addr32);   ce<4,1>(kv, lane, addr32);
    ce<8,4>(kv, lane, addr32);   ce<8,2>(kv, lane, addr32);   ce<8,1>(kv, lane, addr32);
    ce<16,8>(kv, lane, addr32);  ce<16,4>(kv, lane, addr32);  ce<16,2>(kv, lane, addr32);  ce<16,1>(kv, lane, addr32);
    ce<32,16>(kv, lane, addr32); ce<32,8>(kv, lane, addr32);  ce<32,4>(kv, lane, addr32);  ce<32,2>(kv, lane, addr32);  ce<32,1>(kv, lane, addr32);
    clean64(kv, lane, addr32);
    return kv;
}

#define PAD_RAW 0x7F800000FFFFFFFFull   // raw:+inf bits, idx:~0 -> transforms to u64 max

// Flush: transform raw buffer -> sort keys, bitonic sort, reversal-merge into
// the sorted list, clean, tighten worst_f, reset buffer to pad.
__device__ __forceinline__ void flush_merge(u64 &kv, float &worst_f,
                                            u64* __restrict__ s_buf,
                                            int lane, int addr32, int addr63) {
    const u64 raw = s_buf[lane];
    unsigned hi = (unsigned)(raw >> 32);
    hi ^= (unsigned)((int)hi >> 31) | 0x80000000u;           // order-preserving
    u64 kvb = ((u64)hi << 32) | (unsigned)raw;
    kvb = sort64(kvb, lane, addr32);
    // reversal-merge: kv[i] = min(list[i], buf_sorted[63-i]) -> bitonic
    const unsigned rlo = (unsigned)__builtin_amdgcn_ds_bpermute(addr63, (int)(unsigned)kvb);
    const unsigned rhi = (unsigned)__builtin_amdgcn_ds_bpermute(addr63, (int)(unsigned)(kvb >> 32));
    const u64 r = ((u64)rhi << 32) | (u64)rlo;
    kv = (r < kv) ? r : kv;
    clean64(kv, lane, addr32);
    unsigned w = (unsigned)__builtin_amdgcn_readlane((int)(unsigned)(kv >> 32), 63);
    w ^= (w & 0x80000000u) ? 0x80000000u : 0xFFFFFFFFu;      // untransform (pad -> +inf)
    worst_f = __uint_as_float(w);
    s_buf[lane] = PAD_RAW;
}

__global__ __launch_bounds__(256) void knn_wave_kernel(
    const float4* __restrict__ coords,
    float* __restrict__ outIdx,
    float* __restrict__ outDist,
    int S, int Nq)
{
#pragma clang fp contract(off)
    extern __shared__ u64 smem_u64[];              // [S/2] csq floats + 4*64 u64 buf
    float* __restrict__ s_csq = (float*)smem_u64;

    const int tid   = threadIdx.x;
    const int lane  = tid & 63;
    const int wid   = tid >> 6;
    const int qbase = blockIdx.x << 2;             // 4 queries/block, same segment
    const int seg_start = (qbase / S) * S;         // S % 4 == 0 (S=4096)

    // ---- cooperative csq fill (identical butterfly, contract off) ----
    for (int p = tid; p < S; p += 256) {
        const float4 c = coords[seg_start + p];
        s_csq[p] = (c.x * c.x + c.z * c.z) + (c.y * c.y + c.w * c.w);
    }
    __syncthreads();

    const int q = qbase + wid;
    if (q >= Nq) return;                           // wave-uniform, after sync

    u64* __restrict__ s_buf = smem_u64 + (S >> 1) + (wid << 6);  // 64 slots/wave
    const float4* __restrict__ seg = coords + seg_start;

    const float4 x = coords[q];
    const float sqx = (x.x * x.x + x.z * x.z) + (x.y * x.y + x.w * x.w);

    const int addr32 = (lane ^ 32) << 2;
    const int addr63 = (lane ^ 63) << 2;

    u64 kv = 0xFF800000FFFFFFFFull;                // all-pad sorted list (transformed)
    float worst_f = __builtin_inff();
    s_buf[lane] = PAD_RAW;
    int bufcnt = 0;

    const int S4 = S & ~255;                       // main: 4 chunks per iteration
    for (int c0 = 0; c0 < S4; c0 += 256) {
#pragma unroll
        for (int u = 0; u < 4; ++u) {
            const int base = c0 + (u << 6);
            const int j = base + lane;
            const float4 c = seg[j];               // imm-offset foldable (±4KB)
            const float csq = s_csq[j];
            const float dot = __builtin_fmaf(x.w, c.w,
                              __builtin_fmaf(x.z, c.z,
                              __builtin_fmaf(x.y, c.y, x.x * c.x)));
            const float d2  = __builtin_fmaf(-2.0f, dot, sqx + csq);

            bool surv = d2 < worst_f;              // float order == key order here
            u64 m = __ballot(surv);
            int cnt = __popcll(m);
            if (bufcnt + cnt > 64) {               // wave-uniform
                flush_merge(kv, worst_f, s_buf, lane, addr32, addr63);
                bufcnt = 0;
                surv = d2 < worst_f;               // re-ballot vs tightened worst
                m = __ballot(surv);
                cnt = __popcll(m);
            }
            if (m) {                               // skip empty chunks (wave-uniform)
                const int pos = __builtin_amdgcn_mbcnt_hi(
                                    (unsigned)(m >> 32),
                                    __builtin_amdgcn_mbcnt_lo((unsigned)m, bufcnt));
                if (surv)
                    s_buf[pos] = ((u64)__float_as_uint(d2) << 32) | (unsigned)j;
                bufcnt += cnt;
            }
        }
    }
    for (int c0 = S4; c0 < S; c0 += 64) {          // generic tail (S%256!=0 safety)
        const int j = c0 + lane;
        const float4 c = seg[j];
        const float csq = s_csq[j];
        const float dot = __builtin_fmaf(x.w, c.w,
                          __builtin_fmaf(x.z, c.z,
                          __builtin_fmaf(x.y, c.y, x.x * c.x)));
        const float d2  = __builtin_fmaf(-2.0f, dot, sqx + csq);
        bool surv = d2 < worst_f;
        u64 m = __ballot(surv);
        int cnt = __popcll(m);
        if (bufcnt + cnt > 64) {
            flush_merge(kv, worst_f, s_buf, lane, addr32, addr63);
            bufcnt = 0;
            surv = d2 < worst_f;
            m = __ballot(surv);
            cnt = __popcll(m);
        }
        if (m) {
            const int pos = __builtin_amdgcn_mbcnt_hi(
                                (unsigned)(m >> 32),
                                __builtin_amdgcn_mbcnt_lo((unsigned)m, bufcnt));
            if (surv)
                s_buf[pos] = ((u64)__float_as_uint(d2) << 32) | (unsigned)j;
            bufcnt += cnt;
        }
    }

    if (bufcnt > 0)
        flush_merge(kv, worst_f, s_buf, lane, addr32, addr63);

    // lane l holds rank l: fully coalesced 64-wide stores
    const unsigned idxs = (unsigned)kv;
    unsigned bk = (unsigned)(kv >> 32);
    bk ^= ((bk & 0x80000000u) ? 0x80000000u : 0xFFFFFFFFu);  // undo transform
    const float d2 = __uint_as_float(bk);
    outIdx [(size_t)q * KNN + lane] = (float)(seg_start + (int)idxs);
    outDist[(size_t)q * KNN + lane] = fmaxf(d2, 0.0f);
}

extern "C" void kernel_launch(void* const* d_in, const int* in_sizes, int n_in,
                              void* d_out, int out_size, void* d_ws, size_t ws_size,
                              hipStream_t stream) {
    const float* coords = (const float*)d_in[1];
    const int N = in_sizes[1] / 4;
    const int B = in_sizes[2] - 1;
    const int S = N / B;
    (void)n_in; (void)d_ws; (void)ws_size; (void)out_size;

    float* outIdx  = (float*)d_out;
    float* outDist = outIdx + (size_t)N * KNN;

    const int blocks = (N + 3) / 4;                // 4 waves (queries) per block
    const size_t smem = (size_t)S * 4 + 4 * 64 * 8;  // csq + 4 wave buffers
    knn_wave_kernel<<<blocks, 256, smem, stream>>>((const float4*)coords,
                                                   outIdx, outDist, S, N);
}